// Round 6
// baseline (386.150 us; speedup 1.0000x reference)
//
#include <hip/hip_runtime.h>
#include <stdint.h>

#define SEQ 2048
#define BATCH 2
#define HID 2048
#define NHEADS 16
#define HDIM 128
#define QKV_LD 6144
#define SCALE_F 0.08838834764831845f
#define LOG2E_F 1.4426950408889634f

typedef unsigned short u16;
using bf16x8 = __attribute__((ext_vector_type(8))) short;
using f32x4  = __attribute__((ext_vector_type(4))) float;

__device__ inline u16 f2bf(float f) {
  union { float f; uint32_t u; } c; c.f = f;
  uint32_t u = c.u;
  uint32_t r = (u + 0x7fffu + ((u >> 16) & 1u)) >> 16;
  return (u16)r;
}

__device__ inline void gl_lds16(const u16* g, u16* l) {
  __builtin_amdgcn_global_load_lds((const __attribute__((address_space(1))) void*)g,
                                   (__attribute__((address_space(3))) void*)l,
                                   16, 0, 0);
}

// One kernel converts all three inputs. Outputs are contiguous in ws:
// [hs_bf | wqkv_bf (Q rows pre-scaled) | wout_bf], indexed as ushort4.
__global__ void cvt_all(const float* __restrict__ hs, const float* __restrict__ wqkv,
                        const float* __restrict__ wout, u16* __restrict__ ws_out) {
  int i = blockIdx.x * blockDim.x + threadIdx.x;   // 0 .. 6291456 float4-groups
  const float* src;
  int j;
  float sc = 1.0f;
  if (i < 2097152) { src = hs; j = i; }
  else if (i < 5242880) {
    j = i - 2097152; src = wqkv;
    const int f = j >> 9;                          // w_qkv row (2048 f32 = 512 float4 per row)
    if ((f % 384) < 128) sc = SCALE_F;             // Q rows carry the softmax scale
  } else { j = i - 5242880; src = wout; }
  float4 v = ((const float4*)src)[j];
  ushort4 o;
  o.x = f2bf(v.x * sc); o.y = f2bf(v.y * sc); o.z = f2bf(v.z * sc); o.w = f2bf(v.w * sc);
  ((ushort4*)ws_out)[i] = o;
}

// C[M,N] = A[M,K] @ B[N,K]^T, bf16 in, fp32 acc. 128x128 tile, BK=64, gl_lds x16
// staging with XOR chunk swizzle (slot = c ^ (row&7)): 0 bank conflicts (R5 measured).
template<bool OUT_BF16>
__global__ __launch_bounds__(256)
void gemm_bt(const u16* __restrict__ A, const u16* __restrict__ Bw,
             void* __restrict__ Cout, int M, int N, int K) {
  __shared__ __align__(16) u16 As[128 * 64];
  __shared__ __align__(16) u16 Bs[128 * 64];
  const int bm = blockIdx.x, bn = blockIdx.y;
  const int tid = threadIdx.x;
  const int wave = tid >> 6, lane = tid & 63;
  const int quad = lane >> 4, l16 = lane & 15;
  const int wm = (wave >> 1) * 64, wn = (wave & 1) * 64;
  f32x4 acc[4][4] = {};

  const u16* Ablk = A + (size_t)(bm * 128) * K;
  const u16* Bblk = Bw + (size_t)(bn * 128) * K;

  for (int k0 = 0; k0 < K; k0 += 64) {
    __syncthreads();
    #pragma unroll
    for (int p = 0; p < 4; ++p) {
      int j = p * 256 + tid;
      int r = j >> 3, cs = j & 7, c = cs ^ (r & 7);
      gl_lds16(Ablk + (size_t)r * K + k0 + c * 8, As + (p * 256 + wave * 64) * 8);
      gl_lds16(Bblk + (size_t)r * K + k0 + c * 8, Bs + (p * 256 + wave * 64) * 8);
    }
    __syncthreads();
    #pragma unroll
    for (int ks = 0; ks < 2; ++ks) {
      bf16x8 af[4], bfr[4];
      #pragma unroll
      for (int mt = 0; mt < 4; ++mt) {
        int row = wm + mt * 16 + l16;
        int cc = (ks * 4 + quad) ^ (row & 7);
        af[mt] = *(const bf16x8*)&As[(row * 8 + cc) * 8];
      }
      #pragma unroll
      for (int nt = 0; nt < 4; ++nt) {
        int row = wn + nt * 16 + l16;
        int cc = (ks * 4 + quad) ^ (row & 7);
        bfr[nt] = *(const bf16x8*)&Bs[(row * 8 + cc) * 8];
      }
      #pragma unroll
      for (int mt = 0; mt < 4; ++mt)
        #pragma unroll
        for (int nt = 0; nt < 4; ++nt)
          acc[mt][nt] = __builtin_amdgcn_mfma_f32_16x16x32_bf16(af[mt], bfr[nt], acc[mt][nt], 0, 0, 0);
    }
  }

  #pragma unroll
  for (int mt = 0; mt < 4; ++mt) {
    #pragma unroll
    for (int nt = 0; nt < 4; ++nt) {
      #pragma unroll
      for (int r = 0; r < 4; ++r) {
        int row = bm * 128 + wm + mt * 16 + quad * 4 + r;
        int col = bn * 128 + wn + nt * 16 + l16;
        float v = acc[mt][nt][r];
        if (OUT_BF16) ((u16*)Cout)[(size_t)row * N + col] = f2bf(v);
        else          ((float*)Cout)[(size_t)row * N + col] = v;
      }
    }
  }
}

// V transpose: qkv[token][h*384+256..384] -> vt[(b*NH+head)*128+hd][seq].
__global__ __launch_bounds__(256)
void transpose_v(const u16* __restrict__ qkv, u16* __restrict__ vt) {
  __shared__ u16 Vs[64][132];
  const int st = blockIdx.x, head = blockIdx.y, b = blockIdx.z;
  const int s0 = st * 64;
  const int t = threadIdx.x;
  {
    const int r = t >> 2, c0 = (t & 3) * 32;
    const u16* src = qkv + ((size_t)(s0 + r) * BATCH + b) * QKV_LD + head * 384 + 256 + c0;
    #pragma unroll
    for (int j = 0; j < 4; ++j)
      *(uint4*)&Vs[r][c0 + j * 8] = *(const uint4*)(src + j * 8);
  }
  __syncthreads();
  {
    const int hd = t & 127, sc = (t >> 7) * 32;
    u16 tmp[32];
    #pragma unroll
    for (int j = 0; j < 32; ++j) tmp[j] = Vs[sc + j][hd];
    u16* dst = vt + ((size_t)(b * NHEADS + head) * HDIM + hd) * SEQ + s0 + sc;
    #pragma unroll
    for (int j = 0; j < 4; ++j)
      *(uint4*)&dst[j * 8] = *(const uint4*)&tmp[j * 8];
  }
}

// Flash attention, no-max softmax (Q pre-scaled; scores bounded so exp can't overflow).
// R6: 512 threads / 8 waves / 256 q-rows per block — each 64-key staging round (34 KB)
// now feeds 8 waves instead of 4, halving barrier-drain events and L2 traffic per unit
// work. Grid 8x16x2 = 256 blocks = 1/CU. LDS 70 KB. Per-wave structure unchanged.
// l computed by MFMA against a ones-row appended as V-tile nt=8 (hd=128).
__global__ __launch_bounds__(512, 2)
void attn(const u16* __restrict__ qkv, const u16* __restrict__ vt_g, u16* __restrict__ ctx) {
  const int qt = blockIdx.x, head = blockIdx.y, b = blockIdx.z;
  const int q0 = qt * 256;
  __shared__ __align__(16) u16 Ks[64 * 128];   // 16 KB: 64 rows x 16 chunks of 16B
  __shared__ __align__(16) u16 Vt[144 * 64];   // 18 KB: 128 V rows + 16 ones/zero rows
  __shared__ __align__(16) u16 Ps[256 * 72];   // 36 KB, LD=72 u16, wave-private 32-row bands
  const int tid = threadIdx.x;
  const int wave = tid >> 6, lane = tid & 63;
  const int quad = lane >> 4, l16 = lane & 15;

  const u16* qkv_bh = qkv + (size_t)b * QKV_LD + head * 384;
  const u16* vt = vt_g + (size_t)(b * NHEADS + head) * HDIM * SEQ;

  // ones/zero rows 128..143 of Vt (row 128 = 1.0 bf16, rest 0); written once.
  if (tid < 128) {
    const int row = 128 + (tid >> 3), c = tid & 7;
    const u16 v = (row == 128) ? (u16)0x3F80 : (u16)0;
    ushort4 q4; q4.x = v; q4.y = v; q4.z = v; q4.w = v;
    *(ushort4*)&Vt[(row * 8 + c) * 8] = q4;
    *(ushort4*)&Vt[(row * 8 + c) * 8 + 4] = q4;
  }

  // ---- stage Q through Ks buffer (4 rounds of 64 rows), frags into registers ----
  bf16x8 qf[2][4];
  #pragma unroll
  for (int h = 0; h < 4; ++h) {
    __syncthreads();
    #pragma unroll
    for (int p = 0; p < 2; ++p) {
      int j = p * 512 + tid;
      int r = j >> 4, cs = j & 15, c = cs ^ (r & 7);
      gl_lds16(qkv_bh + (size_t)(q0 + h * 64 + r) * (BATCH * QKV_LD) + c * 8,
               Ks + (p * 512 + wave * 64) * 8);
    }
    __syncthreads();
    if ((wave >> 1) == h) {
      #pragma unroll
      for (int mt = 0; mt < 2; ++mt)
        #pragma unroll
        for (int ks = 0; ks < 4; ++ks) {
          int row = (wave & 1) * 32 + mt * 16 + l16;
          int cc = (ks * 4 + quad) ^ (row & 7);
          qf[mt][ks] = *(const bf16x8*)&Ks[(row * 16 + cc) * 8];
        }
    }
  }

  f32x4 o[2][9] = {};   // nt=8 column 0 accumulates l

  for (int kt = 0; kt < SEQ; kt += 64) {
    __syncthreads();
    // stage K tile (64 rows x 16 chunks = 1024 chunks)
    #pragma unroll
    for (int p = 0; p < 2; ++p) {
      int j = p * 512 + tid;
      int r = j >> 4, cs = j & 15, c = cs ^ (r & 7);
      gl_lds16(qkv_bh + (size_t)(kt + r) * (BATCH * QKV_LD) + 128 + c * 8,
               Ks + (p * 512 + wave * 64) * 8);
    }
    // stage Vt tile (128 rows x 8 chunks = 1024 chunks)
    #pragma unroll
    for (int p = 0; p < 2; ++p) {
      int j = p * 512 + tid;
      int hd = j >> 3, cs = j & 7, c = cs ^ (hd & 7);
      gl_lds16(vt + (size_t)hd * SEQ + kt + c * 8,
               Vt + (p * 512 + wave * 64) * 8);
    }
    __syncthreads();

    // S = Q K^T  (wave: 32 q-rows x 64 keys); Q already carries SCALE
    f32x4 s[2][4] = {};
    #pragma unroll
    for (int ks = 0; ks < 4; ++ks) {
      bf16x8 bk[4];
      #pragma unroll
      for (int nt = 0; nt < 4; ++nt) {
        int row = nt * 16 + l16;
        int cc = (ks * 4 + quad) ^ (row & 7);
        bk[nt] = *(const bf16x8*)&Ks[(row * 16 + cc) * 8];
      }
      #pragma unroll
      for (int mt = 0; mt < 2; ++mt)
        #pragma unroll
        for (int nt = 0; nt < 4; ++nt)
          s[mt][nt] = __builtin_amdgcn_mfma_f32_16x16x32_bf16(qf[mt][ks], bk[nt], s[mt][nt], 0, 0, 0);
    }

    // p = exp2(s*log2e) -> bf16 -> Ps (l comes from the ones-row MFMA)
    #pragma unroll
    for (int mt = 0; mt < 2; ++mt)
      #pragma unroll
      for (int r = 0; r < 4; ++r) {
        const int prow = (wave * 32 + mt * 16 + quad * 4 + r) * 72;
        #pragma unroll
        for (int nt = 0; nt < 4; ++nt) {
          float ex = __builtin_amdgcn_exp2f(s[mt][nt][r] * LOG2E_F);
          union { float f; uint32_t u; } cv; cv.f = ex;
          Ps[prow + nt * 16 + l16] = (u16)(cv.u >> 16);
        }
      }

    // O += P V, plus l in nt=8 (Ps rows are wave-private; in-wave lgkm ordering suffices)
    #pragma unroll
    for (int ks = 0; ks < 2; ++ks) {
      bf16x8 ap[2], bv[9];
      #pragma unroll
      for (int mt = 0; mt < 2; ++mt)
        ap[mt] = *(const bf16x8*)&Ps[(wave * 32 + mt * 16 + l16) * 72 + ks * 32 + quad * 8];
      #pragma unroll
      for (int nt = 0; nt < 9; ++nt) {
        int hd = nt * 16 + l16;
        int cc = (ks * 4 + quad) ^ (hd & 7);
        bv[nt] = *(const bf16x8*)&Vt[(hd * 8 + cc) * 8];
      }
      #pragma unroll
      for (int mt = 0; mt < 2; ++mt)
        #pragma unroll
        for (int nt = 0; nt < 9; ++nt)
          o[mt][nt] = __builtin_amdgcn_mfma_f32_16x16x32_bf16(ap[mt], bv[nt], o[mt][nt], 0, 0, 0);
    }
  }

  // epilogue: l sits in o[mt][8][r] at l16==0 lanes of each quad; broadcast within quad
  #pragma unroll
  for (int mt = 0; mt < 2; ++mt)
    #pragma unroll
    for (int r = 0; r < 4; ++r) {
      const float lv = __shfl(o[mt][8][r], lane & 48);
      const float inv_l = 1.0f / lv;
      const int srow = q0 + wave * 32 + mt * 16 + quad * 4 + r;
      u16* dst = ctx + ((size_t)srow * BATCH + b) * HID + head * HDIM;
      #pragma unroll
      for (int nt = 0; nt < 8; ++nt)
        dst[nt * 16 + l16] = f2bf(o[mt][nt][r] * inv_l);
    }
}

extern "C" void kernel_launch(void* const* d_in, const int* in_sizes, int n_in,
                              void* d_out, int out_size, void* d_ws, size_t ws_size,
                              hipStream_t stream) {
  const float* hs   = (const float*)d_in[0];
  const float* wqkv = (const float*)d_in[1];
  const float* wout = (const float*)d_in[2];
  float* out = (float*)d_out;
  char* ws = (char*)d_ws;

  u16* hs_bf   = (u16*)(ws);               // 16777216 B (dead after QKV GEMM)
  u16* wqkv_bf = (u16*)(ws + 16777216);    // 25165824 B
  u16* wout_bf = (u16*)(ws + 41943040);    //  8388608 B
  u16* qkv_bf  = (u16*)(ws + 50331648);    // 50331648 B
  u16* ctx_bf  = (u16*)(ws + 100663296);   // 16777216 B
  u16* vt_bf   = hs_bf;                    // reuse (transpose_v runs after QKV GEMM)

  cvt_all<<<24576, 256, 0, stream>>>(hs, wqkv, wout, (u16*)ws);

  gemm_bt<true><<<dim3(32, 48), 256, 0, stream>>>(hs_bf, wqkv_bf, qkv_bf, 4096, 6144, 2048);

  transpose_v<<<dim3(32, NHEADS, BATCH), 256, 0, stream>>>(qkv_bf, vt_bf);

  attn<<<dim3(8, NHEADS, BATCH), 512, 0, stream>>>(qkv_bf, vt_bf, ctx_bf);

  gemm_bt<false><<<dim3(32, 16), 256, 0, stream>>>(ctx_bf, wout_bf, out, 4096, 2048, 2048);
}

// Round 7
// 373.112 us; speedup vs baseline: 1.0349x; 1.0349x over previous
//
#include <hip/hip_runtime.h>
#include <stdint.h>

#define SEQ 2048
#define BATCH 2
#define HID 2048
#define NHEADS 16
#define HDIM 128
#define QKV_LD 6144
#define SCALE_F 0.08838834764831845f
#define LOG2E_F 1.4426950408889634f

typedef unsigned short u16;
using bf16x8 = __attribute__((ext_vector_type(8))) short;
using f32x4  = __attribute__((ext_vector_type(4))) float;

__device__ inline u16 f2bf(float f) {
  union { float f; uint32_t u; } c; c.f = f;
  uint32_t u = c.u;
  uint32_t r = (u + 0x7fffu + ((u >> 16) & 1u)) >> 16;
  return (u16)r;
}

__device__ inline void gl_lds16(const u16* g, u16* l) {
  __builtin_amdgcn_global_load_lds((const __attribute__((address_space(1))) void*)g,
                                   (__attribute__((address_space(3))) void*)l,
                                   16, 0, 0);
}

// One kernel converts all three inputs. Outputs contiguous in ws:
// [hs_bf | wqkv_bf (Q rows pre-scaled) | wout_bf].
__global__ void cvt_all(const float* __restrict__ hs, const float* __restrict__ wqkv,
                        const float* __restrict__ wout, u16* __restrict__ ws_out) {
  int i = blockIdx.x * blockDim.x + threadIdx.x;
  const float* src;
  int j;
  float sc = 1.0f;
  if (i < 2097152) { src = hs; j = i; }
  else if (i < 5242880) {
    j = i - 2097152; src = wqkv;
    const int f = j >> 9;
    if ((f % 384) < 128) sc = SCALE_F;             // Q rows carry the softmax scale
  } else { j = i - 5242880; src = wout; }
  float4 v = ((const float4*)src)[j];
  ushort4 o;
  o.x = f2bf(v.x * sc); o.y = f2bf(v.y * sc); o.z = f2bf(v.z * sc); o.w = f2bf(v.w * sc);
  ((ushort4*)ws_out)[i] = o;
}

// C[M,N] = A[M,K] @ B[N,K]^T, bf16 in, fp32 acc. 128x128 tile, BK=64, gl_lds x16
// staging with XOR chunk swizzle (0 bank conflicts, R5-measured).
// MODE 1 (QKV): bf16 out; V-blocks (bn%3==2, head=bn/3) written TRANSPOSED to vt
//   as packed 4B stores (two seq-positions per store), qkv V-part not written.
// MODE 0: f32 out, no vt.
template<int MODE>
__global__ __launch_bounds__(256)
void gemm_bt(const u16* __restrict__ A, const u16* __restrict__ Bw,
             void* __restrict__ Cout, u16* __restrict__ vt, int M, int N, int K) {
  __shared__ __align__(16) u16 As[128 * 64];
  __shared__ __align__(16) u16 Bs[128 * 64];
  const int bm = blockIdx.x, bn = blockIdx.y;
  const int tid = threadIdx.x;
  const int wave = tid >> 6, lane = tid & 63;
  const int quad = lane >> 4, l16 = lane & 15;
  const int wm = (wave >> 1) * 64, wn = (wave & 1) * 64;
  f32x4 acc[4][4] = {};

  const u16* Ablk = A + (size_t)(bm * 128) * K;
  const u16* Bblk = Bw + (size_t)(bn * 128) * K;

  for (int k0 = 0; k0 < K; k0 += 64) {
    __syncthreads();
    #pragma unroll
    for (int p = 0; p < 4; ++p) {
      int j = p * 256 + tid;
      int r = j >> 3, cs = j & 7, c = cs ^ (r & 7);
      gl_lds16(Ablk + (size_t)r * K + k0 + c * 8, As + (p * 256 + wave * 64) * 8);
      gl_lds16(Bblk + (size_t)r * K + k0 + c * 8, Bs + (p * 256 + wave * 64) * 8);
    }
    __syncthreads();
    #pragma unroll
    for (int ks = 0; ks < 2; ++ks) {
      bf16x8 af[4], bfr[4];
      #pragma unroll
      for (int mt = 0; mt < 4; ++mt) {
        int row = wm + mt * 16 + l16;
        int cc = (ks * 4 + quad) ^ (row & 7);
        af[mt] = *(const bf16x8*)&As[(row * 8 + cc) * 8];
      }
      #pragma unroll
      for (int nt = 0; nt < 4; ++nt) {
        int row = wn + nt * 16 + l16;
        int cc = (ks * 4 + quad) ^ (row & 7);
        bfr[nt] = *(const bf16x8*)&Bs[(row * 8 + cc) * 8];
      }
      #pragma unroll
      for (int mt = 0; mt < 4; ++mt)
        #pragma unroll
        for (int nt = 0; nt < 4; ++nt)
          acc[mt][nt] = __builtin_amdgcn_mfma_f32_16x16x32_bf16(af[mt], bfr[nt], acc[mt][nt], 0, 0, 0);
    }
  }

  if (MODE == 1 && (bn % 3) == 2) {
    // V block: C rows are tokens (row = s*2+b), cols are head-dims hd of head bn/3.
    // r=0:(s0,b0) r=1:(s0,b1) r=2:(s0+1,b0) r=3:(s0+1,b1); pack (r0,r2)/(r1,r3) -> 4B.
    const int h = bn / 3;
    u16* vt0 = vt + ((size_t)h * HDIM) * SEQ;                     // b=0
    u16* vt1 = vt + ((size_t)(NHEADS + h) * HDIM) * SEQ;          // b=1
    #pragma unroll
    for (int mt = 0; mt < 4; ++mt)
      #pragma unroll
      for (int nt = 0; nt < 4; ++nt) {
        const int hd = wn + nt * 16 + l16;
        const int s0 = (bm * 128 + wm + mt * 16 + quad * 4) >> 1;
        uint32_t w0 = (uint32_t)f2bf(acc[mt][nt][0]) | ((uint32_t)f2bf(acc[mt][nt][2]) << 16);
        uint32_t w1 = (uint32_t)f2bf(acc[mt][nt][1]) | ((uint32_t)f2bf(acc[mt][nt][3]) << 16);
        *(uint32_t*)&vt0[(size_t)hd * SEQ + s0] = w0;
        *(uint32_t*)&vt1[(size_t)hd * SEQ + s0] = w1;
      }
    return;
  }

  #pragma unroll
  for (int mt = 0; mt < 4; ++mt)
    #pragma unroll
    for (int nt = 0; nt < 4; ++nt)
      #pragma unroll
      for (int r = 0; r < 4; ++r) {
        int row = bm * 128 + wm + mt * 16 + quad * 4 + r;
        int col = bn * 128 + wn + nt * 16 + l16;
        float v = acc[mt][nt][r];
        if (MODE == 1) ((u16*)Cout)[(size_t)row * N + col] = f2bf(v);
        else           ((float*)Cout)[(size_t)row * N + col] = v;
      }
}

// Flash attention, no-max softmax (Q pre-scaled; scores bounded so exp can't overflow).
// R7: transposed formulation. S^T = K Q^T (A=K frags from LDS, B=Q frags in regs —
// B-operand register layout == A-operand layout, validated R1-R6). P^T written to LDS
// as 8 ds_write_b64 (XOR-swizzled) instead of 32 ds_write_b16. O^T = V P via A=Vt
// (b128 rows), B=P^T (b128). l via ones-rows (Vt rows 128..143, row 128 = 1.0).
// Epilogue: 16 packed 8B ctx stores per lane instead of 64 scalar u16.
__global__ __launch_bounds__(512, 2)
void attn(const u16* __restrict__ qkv, const u16* __restrict__ vt_g, u16* __restrict__ ctx) {
  const int qt = blockIdx.x, head = blockIdx.y, b = blockIdx.z;
  const int q0 = qt * 256;
  __shared__ __align__(16) u16 Ks[64 * 128];    // 16 KB: 64 key-rows x 16 chunks
  __shared__ __align__(16) u16 Vt[144 * 64];    // 18 KB: 128 hd-rows + 16 ones/zero rows
  __shared__ __align__(16) u16 PsT[256 * 64];   // 32 KB: [q][key], swizzled chunks
  const int tid = threadIdx.x;
  const int wave = tid >> 6, lane = tid & 63;
  const int quad = lane >> 4, l16 = lane & 15;

  const u16* qkv_bh = qkv + (size_t)b * QKV_LD + head * 384;
  const u16* vt = vt_g + (size_t)(b * NHEADS + head) * HDIM * SEQ;

  // ones/zero rows 128..143 of Vt (row 128 = 1.0 bf16, rest 0); written once.
  if (tid < 128) {
    const int row = 128 + (tid >> 3), c = tid & 7;
    const u16 v = (row == 128) ? (u16)0x3F80 : (u16)0;
    ushort4 q4; q4.x = v; q4.y = v; q4.z = v; q4.w = v;
    *(ushort4*)&Vt[(row * 8 + c) * 8] = q4;
    *(ushort4*)&Vt[(row * 8 + c) * 8 + 4] = q4;
  }

  // ---- stage Q through Ks buffer (4 rounds of 64 rows), frags into registers ----
  bf16x8 qf[2][4];   // [q-tile nt][ks]; used as B-operand later (same reg layout as A)
  #pragma unroll
  for (int h = 0; h < 4; ++h) {
    __syncthreads();
    #pragma unroll
    for (int p = 0; p < 2; ++p) {
      int j = p * 512 + tid;
      int r = j >> 4, cs = j & 15, c = cs ^ (r & 7);
      gl_lds16(qkv_bh + (size_t)(q0 + h * 64 + r) * (BATCH * QKV_LD) + c * 8,
               Ks + (p * 512 + wave * 64) * 8);
    }
    __syncthreads();
    if ((wave >> 1) == h) {
      #pragma unroll
      for (int nt = 0; nt < 2; ++nt)
        #pragma unroll
        for (int ks = 0; ks < 4; ++ks) {
          int row = (wave & 1) * 32 + nt * 16 + l16;
          int cc = (ks * 4 + quad) ^ (row & 7);
          qf[nt][ks] = *(const bf16x8*)&Ks[(row * 16 + cc) * 8];
        }
    }
  }

  f32x4 ot[9][2] = {};   // [hd-tile mt (8=ones/l)][q-tile nt]

  for (int kt = 0; kt < SEQ; kt += 64) {
    __syncthreads();
    // stage K tile (64 rows x 16 chunks)
    #pragma unroll
    for (int p = 0; p < 2; ++p) {
      int j = p * 512 + tid;
      int r = j >> 4, cs = j & 15, c = cs ^ (r & 7);
      gl_lds16(qkv_bh + (size_t)(kt + r) * (BATCH * QKV_LD) + 128 + c * 8,
               Ks + (p * 512 + wave * 64) * 8);
    }
    // stage Vt tile (128 rows x 8 chunks)
    #pragma unroll
    for (int p = 0; p < 2; ++p) {
      int j = p * 512 + tid;
      int hd = j >> 3, cs = j & 7, c = cs ^ (hd & 7);
      gl_lds16(vt + (size_t)hd * SEQ + kt + c * 8,
               Vt + (p * 512 + wave * 64) * 8);
    }
    __syncthreads();

    // S^T = K Q^T  (wave: 64 keys x 32 q-rows); element (key=mt*16+quad*4+r, q=nt*16+l16)
    f32x4 st[4][2] = {};
    #pragma unroll
    for (int ks = 0; ks < 4; ++ks) {
      bf16x8 kf[4];
      #pragma unroll
      for (int mt = 0; mt < 4; ++mt) {
        int key = mt * 16 + l16;
        int cc = (ks * 4 + quad) ^ (key & 7);
        kf[mt] = *(const bf16x8*)&Ks[(key * 16 + cc) * 8];
      }
      #pragma unroll
      for (int mt = 0; mt < 4; ++mt)
        #pragma unroll
        for (int nt = 0; nt < 2; ++nt)
          st[mt][nt] = __builtin_amdgcn_mfma_f32_16x16x32_bf16(kf[mt], qf[nt][ks], st[mt][nt], 0, 0, 0);
    }

    // p = exp2(s*log2e) -> bf16; 4 consecutive keys per lane -> one b64 write each
    #pragma unroll
    for (int mt = 0; mt < 4; ++mt)
      #pragma unroll
      for (int nt = 0; nt < 2; ++nt) {
        ushort4 pk;
        union { float f; uint32_t u; } cv;
        cv.f = __builtin_amdgcn_exp2f(st[mt][nt][0] * LOG2E_F); pk.x = (u16)(cv.u >> 16);
        cv.f = __builtin_amdgcn_exp2f(st[mt][nt][1] * LOG2E_F); pk.y = (u16)(cv.u >> 16);
        cv.f = __builtin_amdgcn_exp2f(st[mt][nt][2] * LOG2E_F); pk.z = (u16)(cv.u >> 16);
        cv.f = __builtin_amdgcn_exp2f(st[mt][nt][3] * LOG2E_F); pk.w = (u16)(cv.u >> 16);
        const int q = wave * 32 + nt * 16 + l16;
        const int kc = mt * 2 + (quad >> 1);
        *(ushort4*)&PsT[q * 64 + ((kc ^ (l16 & 7)) * 8 + (quad & 1) * 4)] = pk;
      }

    // O^T += V P  (A=Vt rows incl. ones, B=P^T; PsT rows are wave-private)
    #pragma unroll
    for (int ks = 0; ks < 2; ++ks) {
      bf16x8 pf[2], vf[9];
      #pragma unroll
      for (int nt = 0; nt < 2; ++nt) {
        const int q = wave * 32 + nt * 16 + l16;
        const int cc = (ks * 4 + quad) ^ (l16 & 7);
        pf[nt] = *(const bf16x8*)&PsT[q * 64 + cc * 8];
      }
      #pragma unroll
      for (int mt = 0; mt < 9; ++mt) {
        const int hd = mt * 16 + l16;
        const int cc = (ks * 4 + quad) ^ (hd & 7);
        vf[mt] = *(const bf16x8*)&Vt[(hd * 8 + cc) * 8];
      }
      #pragma unroll
      for (int mt = 0; mt < 9; ++mt)
        #pragma unroll
        for (int nt = 0; nt < 2; ++nt)
          ot[mt][nt] = __builtin_amdgcn_mfma_f32_16x16x32_bf16(vf[mt], pf[nt], ot[mt][nt], 0, 0, 0);
    }
  }

  // epilogue: l[q] lives in ot[8][nt][0] at quad-0 lanes (m=0 row of ones-tile)
  #pragma unroll
  for (int nt = 0; nt < 2; ++nt) {
    const float lv = __shfl(ot[8][nt][0], l16);
    const float inv_l = 1.0f / lv;
    const int s = q0 + wave * 32 + nt * 16 + l16;
    u16* dst = ctx + ((size_t)s * BATCH + b) * HID + head * HDIM;
    #pragma unroll
    for (int mt = 0; mt < 8; ++mt) {
      ushort4 w;
      w.x = f2bf(ot[mt][nt][0] * inv_l);
      w.y = f2bf(ot[mt][nt][1] * inv_l);
      w.z = f2bf(ot[mt][nt][2] * inv_l);
      w.w = f2bf(ot[mt][nt][3] * inv_l);
      *(ushort4*)&dst[mt * 16 + quad * 4] = w;
    }
  }
}

extern "C" void kernel_launch(void* const* d_in, const int* in_sizes, int n_in,
                              void* d_out, int out_size, void* d_ws, size_t ws_size,
                              hipStream_t stream) {
  const float* hs   = (const float*)d_in[0];
  const float* wqkv = (const float*)d_in[1];
  const float* wout = (const float*)d_in[2];
  float* out = (float*)d_out;
  char* ws = (char*)d_ws;

  u16* hs_bf   = (u16*)(ws);               // 16 MB; dead after QKV GEMM
  u16* wqkv_bf = (u16*)(ws + 16777216);    // 24 MB
  u16* wout_bf = (u16*)(ws + 41943040);    //  8 MB
  u16* qkv_bf  = (u16*)(ws + 50331648);    // 48 MB (V-part unused/unwritten)
  u16* vt_bf   = (u16*)(ws + 100663296);   // 16 MB, written by QKV GEMM epilogue
  u16* ctx_bf  = hs_bf;                    // reuse: attn runs after QKV GEMM

  cvt_all<<<24576, 256, 0, stream>>>(hs, wqkv, wout, (u16*)ws);

  gemm_bt<1><<<dim3(32, 48), 256, 0, stream>>>(hs_bf, wqkv_bf, qkv_bf, vt_bf, 4096, 6144, 2048);

  attn<<<dim3(8, NHEADS, BATCH), 512, 0, stream>>>(qkv_bf, vt_bf, ctx_bf);

  gemm_bt<0><<<dim3(32, 16), 256, 0, stream>>>(ctx_bf, wout_bf, out, nullptr, 4096, 2048, 2048);
}